// Round 1
// baseline (502.925 us; speedup 1.0000x reference)
//
#include <hip/hip_runtime.h>
#include <hip/hip_bf16.h>

// Problem constants (fixed by reference):
//   frames: (B=4, S=8, N=2, C=4, H=480, W=640) f32  -> dense (32, 8, 480, 640)
//   mask  = max_c |dense[bf,c,y,x]| > 3.0
//   emit first 200000 survivors in (bf,y,x) row-major order
//   out = [features 200000x8 f32][coords 200000x4 (written as float)]
#define HW        307200        // 480*640
#define W_IMG     640
#define PIXELS    9830400       // 32*480*640
#define NBLK      38400         // PIXELS/256
#define MAXPTS    200000
#define FEAT_OFF  0
#define COORD_OFF 1600000       // 200000*8

// ws layout:
//   [0)                u64 maskWords[NBLK*4]          (1,228,800 B)
//   [1228800)          u32 blockCounts[NBLK]          (  153,600 B)
//   [1382400)          u32 blockOffsets[NBLK]         (  153,600 B)

__global__ __launch_bounds__(256) void mask_kernel(const float* __restrict__ frames,
                                                   unsigned long long* __restrict__ maskWords,
                                                   unsigned* __restrict__ blockCounts) {
    int tid   = threadIdx.x;
    int pixel = blockIdx.x * 256 + tid;
    int bf  = pixel / HW;
    int rem = pixel - bf * HW;
    const float* base = frames + (size_t)bf * 8 * HW + rem;
    float m = 0.0f;
#pragma unroll
    for (int c = 0; c < 8; ++c) m = fmaxf(m, fabsf(base[(size_t)c * HW]));
    bool pass = m > 3.0f;
    unsigned long long b = __ballot(pass);
    int wave = tid >> 6, lane = tid & 63;
    __shared__ unsigned cnt[4];
    if (lane == 0) {
        maskWords[(size_t)blockIdx.x * 4 + wave] = b;
        cnt[wave] = (unsigned)__popcll(b);
    }
    __syncthreads();
    if (tid == 0) blockCounts[blockIdx.x] = cnt[0] + cnt[1] + cnt[2] + cnt[3];
}

__global__ __launch_bounds__(256) void scan_kernel(const unsigned* __restrict__ counts,
                                                   unsigned* __restrict__ offsets) {
    __shared__ unsigned s[256];
    int tid = threadIdx.x;
    const int per = (NBLK + 255) / 256;  // 150
    int begin = tid * per;
    int end   = begin + per > NBLK ? NBLK : begin + per;
    unsigned sum = 0;
    for (int i = begin; i < end; ++i) sum += counts[i];
    s[tid] = sum;
    __syncthreads();
    if (tid == 0) {
        unsigned acc = 0;
        for (int i = 0; i < 256; ++i) { unsigned v = s[i]; s[i] = acc; acc += v; }
    }
    __syncthreads();
    unsigned acc = s[tid];
    for (int i = begin; i < end; ++i) { offsets[i] = acc; acc += counts[i]; }
}

__global__ __launch_bounds__(256) void emit_kernel(const float* __restrict__ frames,
                                                   const unsigned long long* __restrict__ maskWords,
                                                   const unsigned* __restrict__ blockOffsets,
                                                   float* __restrict__ out) {
    int tid  = threadIdx.x;
    int wave = tid >> 6, lane = tid & 63;

    __shared__ unsigned wcnt[4];
    __shared__ unsigned long long words[4];
    if (tid < 4) {
        unsigned long long w = maskWords[(size_t)blockIdx.x * 4 + tid];
        words[tid] = w;
        wcnt[tid]  = (unsigned)__popcll(w);
    }
    __syncthreads();

    unsigned long long word = words[wave];
    bool pass = (word >> lane) & 1ULL;
    if (!pass) return;

    unsigned before = 0;
    for (int w = 0; w < wave; ++w) before += wcnt[w];
    unsigned rankInWave = (unsigned)__popcll(word & ((1ULL << lane) - 1ULL));
    unsigned rank = blockOffsets[blockIdx.x] + before + rankInWave;
    if (rank >= MAXPTS) return;

    int pixel = blockIdx.x * 256 + tid;
    int bf  = pixel / HW;
    int rem = pixel - bf * HW;
    int y   = rem / W_IMG;
    int x   = rem - y * W_IMG;

    const float* base = frames + (size_t)bf * 8 * HW + rem;
    float* fo = out + FEAT_OFF + (size_t)rank * 8;
#pragma unroll
    for (int c = 0; c < 8; ++c) fo[c] = base[(size_t)c * HW];

    float* co = out + COORD_OFF + (size_t)rank * 4;
    co[0] = (float)(bf >> 3);   // batch = bf / S, S=8
    co[1] = (float)(bf & 7);    // time  = bf % S
    co[2] = (float)y;
    co[3] = (float)x;
}

extern "C" void kernel_launch(void* const* d_in, const int* in_sizes, int n_in,
                              void* d_out, int out_size, void* d_ws, size_t ws_size,
                              hipStream_t stream) {
    const float* frames = (const float*)d_in[0];
    float* out = (float*)d_out;

    char* ws = (char*)d_ws;
    unsigned long long* maskWords = (unsigned long long*)(ws);
    unsigned* blockCounts  = (unsigned*)(ws + 1228800);
    unsigned* blockOffsets = (unsigned*)(ws + 1382400);

    // zero-fill output (rows >= n_valid must be 0; buffer is poisoned each call)
    hipMemsetAsync(d_out, 0, (size_t)out_size * sizeof(float), stream);

    mask_kernel<<<NBLK, 256, 0, stream>>>(frames, maskWords, blockCounts);
    scan_kernel<<<1, 256, 0, stream>>>(blockCounts, blockOffsets);
    emit_kernel<<<NBLK, 256, 0, stream>>>(frames, maskWords, blockOffsets, out);
}